// Round 12
// baseline (731.384 us; speedup 1.0000x reference)
//
#include <hip/hip_runtime.h>
#include <hip/hip_cooperative_groups.h>
#include <cstdint>

namespace cg = cooperative_groups;

typedef unsigned short u16;
typedef uint32_t u32;

typedef __bf16 bf16x8 __attribute__((ext_vector_type(8)));
typedef float  f32x2  __attribute__((ext_vector_type(2)));
typedef float  f32x4  __attribute__((ext_vector_type(4)));
typedef float  f32x16 __attribute__((ext_vector_type(16)));
typedef u16    u16x4  __attribute__((ext_vector_type(4)));
typedef u16    u16x8  __attribute__((ext_vector_type(8)));

__device__ __forceinline__ u16 f2bf(float f) {
    u32 x = __float_as_uint(f);
    return (u16)((x + 0x7FFFu + ((x >> 16) & 1u)) >> 16);
}
__device__ __forceinline__ float lrelu(float x) { return fmaxf(x, 0.1f * x); }

__device__ __forceinline__ u32 pack_rn(float lo, float hi) {
    u32 a = __float_as_uint(lo) + 0x8000u;
    u32 b = __float_as_uint(hi) + 0x8000u;
    return __builtin_amdgcn_perm(b, a, 0x07060302u);
}

// ---------------------------------------------------------------------------
// Stage P: data-layout prep (1729 units).
// ---------------------------------------------------------------------------
__device__ __forceinline__ void prep_block(int blk, int tid,
    const float* x, const float* conv_w,
    const float* W2, const float* W3, const float* W4,
    const float* b2, const float* b3, const float* b4,
    const float* h, const float* W1,
    u16* xb, u16* wcb_f, u16* wfrag, u16* w1frag,
    float* hW, float* zero0)
{
    if (blk < 1280) {                       // xb
        int o = (blk * 256 + tid) * 4;
        int e = o & 511;
        int bl = o >> 9;
        int b = bl / 160, l = bl % 160;
        f32x4 v = *(const f32x4*)(x + ((size_t)(l * 16 + b)) * 512 + e);
        u16x4 ov;
        ov[0] = f2bf(v[0]); ov[1] = f2bf(v[1]); ov[2] = f2bf(v[2]); ov[3] = f2bf(v[3]);
        *(u16x4*)&xb[o] = ov;
    } else if (blk < 1472) {                // wcb_f
        int g = (blk - 1280) * 256 + tid;
        int lane = g & 63;
        int ks = (g >> 6) % 48;
        int cb = g / 3072;
        int c = cb * 16 + (lane & 15);
        int quad = lane >> 4;
        int k0 = ks * 32 + quad * 8;
        int tap = k0 >> 9, e0 = k0 & 511;
        u16x8 ov;
        #pragma unroll
        for (int j = 0; j < 8; j++)
            ov[j] = f2bf(conv_w[((size_t)c * 512 + e0 + j) * 3 + tap]);
        *(u16x8*)&wcb_f[(size_t)g * 8] = ov;
    } else if (blk < 1526) {                // wfrag
        int o = ((blk - 1472) * 256 + tid) * 4;
        int layer = o / 18432, rem = o % 18432;
        int ks9 = rem >> 11;
        int rem2 = rem & 2047;
        int hh = rem2 >> 10;
        int rem3 = rem2 & 1023;
        int n = rem3 >> 3, j0 = rem3 & 7;
        const float* W = (layer == 0) ? W2 : (layer == 1) ? W3 : W4;
        const float* bi = (layer == 0) ? b2 : (layer == 1) ? b3 : b4;
        u16x4 ov;
        if (ks9 < 8) {
            f32x4 v = *(const f32x4*)(W + (size_t)n * 128 + 16 * ks9 + 8 * hh + j0);
            ov[0] = f2bf(v[0]); ov[1] = f2bf(v[1]); ov[2] = f2bf(v[2]); ov[3] = f2bf(v[3]);
        } else {
            ov[0] = (hh == 0 && j0 == 0) ? f2bf(bi[n]) : (u16)0;
            ov[1] = 0; ov[2] = 0; ov[3] = 0;
        }
        *(u16x4*)&wfrag[o] = ov;
    } else if (blk < 1598) {                // w1frag
        int o = ((blk - 1526) * 256 + tid) * 4;
        int nt = o / 4608;
        int rem = o % 4608;
        int ks = rem >> 9;
        int rem2 = rem & 511;
        int lane = rem2 >> 3, j0 = rem2 & 7;
        int n = nt * 16 + (lane & 15);
        int k0 = ks * 32 + (lane >> 4) * 8 + j0;
        const float* wr = (n < 128) ? (W1 + (size_t)n * 1028)
                                    : (W1 + (size_t)(n - 128) * 1028 + 258);
        u16x4 ov;
        #pragma unroll
        for (int q = 0; q < 4; q++) {
            int k = k0 + q;
            ov[q] = (k < 258) ? f2bf(wr[k]) : (u16)0;
        }
        *(u16x4*)&w1frag[o] = ov;
    } else if (blk < 1726) {                // hW
        int gid = (blk - 1598) * 256 + tid;
        int outp = gid >> 4, q = gid & 15;
        int b = outp >> 7, d = outp & 127;
        const float* hr = h + (size_t)b * 512;
        const float* wr = W1 + (size_t)d * 1028 + 516;
        float acc = 0.f;
        #pragma unroll
        for (int c = 0; c < 8; c++) {
            int k = c * 64 + q * 4;
            f32x4 hv = *(const f32x4*)(hr + k);
            f32x4 wv = *(const f32x4*)(wr + k);
            acc += hv[0]*wv[0] + hv[1]*wv[1] + hv[2]*wv[2] + hv[3]*wv[3];
        }
        acc += __shfl_xor(acc, 1); acc += __shfl_xor(acc, 2);
        acc += __shfl_xor(acc, 4); acc += __shfl_xor(acc, 8);
        if (q == 0) hW[outp] = acc;
    } else {                                // zero s_glob + stats
        int idx = (blk - 1726) * 256 + tid;
        if (idx < 640) {
            f32x4 z = {0.f, 0.f, 0.f, 0.f};
            *(f32x4*)&zero0[idx * 4] = z;
        }
    }
}

// ---------------------------------------------------------------------------
// Stage C: conv1d im2col GEMM (640 units). Trailing barrier so smem can be
// reused by a following strided iteration.
// ---------------------------------------------------------------------------
__device__ __forceinline__ void conv_block(int wg, int tid, u16* xs,
    const u16* xb, const u16* wcb_f, const float* conv_b,
    float* ws_y, float* stats)
{
    int rowtile = wg >> 2, cgp = wg & 3;
    int b = rowtile / 10, l0 = (rowtile % 10) * 16;

    for (int t = tid; t < 18 * 64; t += 256) {
        int s = t >> 6, ch = t & 63;
        int lg = l0 + s - 1;
        u16x8 v = {};
        if (lg >= 0 && lg < 160)
            v = *(const u16x8*)(xb + ((size_t)(b * 160 + lg)) * 512 + ch * 8);
        *(u16x8*)&xs[s * 520 + ch * 8] = v;
    }
    __syncthreads();

    int lane = tid & 63, w = tid >> 6;
    int row16 = lane & 15, quad = lane >> 4;
    int cb = cgp * 4 + w;
    int c_n = cb * 16 + row16;
    const u16* wb = wcb_f + (size_t)cb * 24576;

    f32x4 acc0 = {0,0,0,0};
    for (int ks4 = 0; ks4 < 48; ks4 += 4) {
        bf16x8 wf[4];
        #pragma unroll
        for (int q = 0; q < 4; q++)
            wf[q] = *(const bf16x8*)(wb + (size_t)((ks4 + q) * 64 + lane) * 8);
        #pragma unroll
        for (int q = 0; q < 4; q++) {
            int k = (ks4 + q) * 32 + quad * 8;
            int tap = k >> 9, e = k & 511;
            bf16x8 a0 = *(const bf16x8*)&xs[(row16 + tap) * 520 + e];
            acc0 = __builtin_amdgcn_mfma_f32_16x16x32_bf16(a0, wf[q], acc0, 0, 0, 0);
        }
    }

    float bias = conv_b[c_n];
    float sum = 0.f, sq = 0.f;
    #pragma unroll
    for (int r = 0; r < 4; r++) {
        float v = lrelu(acc0[r] + bias);
        int lr = l0 + quad * 4 + r;
        ws_y[((size_t)(b * 160 + lr)) * 256 + c_n] = v;
        sum += v; sq += v * v;
    }
    sum += __shfl_xor(sum, 16); sum += __shfl_xor(sum, 32);
    sq  += __shfl_xor(sq, 16);  sq  += __shfl_xor(sq, 32);
    if (quad == 0) {
        atomicAdd(&stats[c_n], sum);
        atomicAdd(&stats[256 + c_n], sq);
    }
    __syncthreads();   // xs reads complete before any strided reuse
}

// ---------------------------------------------------------------------------
// Stage U: BN + coords + u/v MFMA GEMM (160 units).
// ---------------------------------------------------------------------------
__device__ __forceinline__ void uv_block(int wg, int tid, unsigned char* smem,
    const float* ws_y, const float* stats,
    const float* bn_g, const float* bn_b,
    const u16* w1frag, const float* b1, const float* hW,
    float* uu, float* vv)
{
    float* a_s = (float*)smem;
    float* c_s = (float*)(smem + 1024);
    u16*   xfs = (u16*)(smem + 2048);        // 16 x 296
    int row0 = wg * 16;
    int b = row0 / 160, l0 = row0 % 160;
    {
        int c = tid;
        float mu  = stats[c] * (1.0f / 2560.0f);
        float var = stats[256 + c] * (1.0f / 2560.0f) - mu * mu;
        float rs  = rsqrtf(var + 1e-5f) * bn_g[c];
        a_s[c] = rs;
        c_s[c] = bn_b[c] - mu * rs;
    }
    __syncthreads();
    float sLf = sqrtf(160.0f);
    for (int idx = tid; idx < 16 * 288; idx += 256) {
        int r = idx / 288, c = idx - r * 288;
        int l = l0 + r;
        float v = 0.f;
        if (c < 256) {
            v = ws_y[((size_t)(b * 160 + l)) * 256 + c] * a_s[c] + c_s[c];
        } else if (c == 256) {
            v = ((float)l / sLf - 2.0f) * 0.5f;
        } else if (c == 257) {
            float fi = (float)l;
            float m = fi - floorf(fi / sLf) * sLf;
            v = (m - 2.0f) * 0.5f;
        }
        xfs[r * 296 + c] = f2bf(v);
    }
    __syncthreads();

    int lane = tid & 63, w = tid >> 6;
    int row16 = lane & 15, quad = lane >> 4;

    bf16x8 af[9];
    #pragma unroll
    for (int ks = 0; ks < 9; ks++)
        af[ks] = *(const bf16x8*)&xfs[row16 * 296 + ks * 32 + quad * 8];

    #pragma unroll
    for (int nt = 0; nt < 4; nt++) {
        f32x4 a = {0.f, 0.f, 0.f, 0.f};
        #pragma unroll
        for (int ks = 0; ks < 9; ks++) {
            bf16x8 bf = *(const bf16x8*)(w1frag +
                (size_t)(((w * 4 + nt) * 9 + ks) * 64 + lane) * 8);
            a = __builtin_amdgcn_mfma_f32_16x16x32_bf16(af[ks], bf, a, 0, 0, 0);
        }
        int n = (w * 4 + nt) * 16 + row16;
        bool isv = n >= 128;
        int d = n & 127;
        float add = isv ? (hW[b * 128 + d] + b1[d]) : 0.f;
        float* dst = isv ? vv : uu;
        #pragma unroll
        for (int r = 0; r < 4; r++) {
            int l = l0 + quad * 4 + r;
            dst[((size_t)(b * 160 + l)) * 128 + d] = a[r] + add;
        }
    }
}

// ---------------------------------------------------------------------------
// Stage M: fused pairwise MLP, one 32-pair tile per wave per unit (3200 units).
// ---------------------------------------------------------------------------
__device__ __forceinline__ void mlp_unit(int unit, int tid,
    u16* Wlds, float* spart,
    const float* vv, const float* uu, const u16* wfrag, float* s_glob)
{
    int wave = tid >> 6, lane = tid & 63;
    int h = lane >> 5, lo = lane & 31;
    int b = unit / 200, sub = unit % 200;
    int tileb = sub * 4 + wave;

    if (tid < 128) spart[tid] = 0.f;

    u32 selv = h ? 0x07060302u : 0x05040100u;
    uint4 biasfrag;
    biasfrag.x = (h == 0) ? 0x00003F80u : 0u;
    biasfrag.y = 0u; biasfrag.z = 0u; biasfrag.w = 0u;

    f32x16 Z;
    #pragma unroll
    for (int r = 0; r < 16; r++) Z[r] = 0.f;

    uint4 B[8], Bn[8];
    float ssum[4];

    int i  = (tileb / 10) * 2  + (lo >> 4);
    int jj = (tileb % 10) * 16 + (lo & 15);
    const float* vr = vv + ((size_t)(b * 160 + i))  * 128 + 8 * h;
    const float* ur = uu + ((size_t)(b * 160 + jj)) * 128 + 8 * h;

    for (int layer = 0; layer < 3; layer++) {
        __syncthreads();
        {
            const uint4* src = (const uint4*)(wfrag + layer * 18432);
            #pragma unroll
            for (int it = 0; it < 9; it++) {
                int idx = it * 256 + tid;
                *(uint4*)&Wlds[idx * 8] = src[idx];
            }
        }
        __syncthreads();

        if (layer == 0) {
            #pragma unroll
            for (int ks = 0; ks < 8; ks++) {
                f32x4 v0 = *(const f32x4*)(vr + 16 * ks);
                f32x4 v1 = *(const f32x4*)(vr + 16 * ks + 4);
                f32x4 u0 = *(const f32x4*)(ur + 16 * ks);
                f32x4 u1 = *(const f32x4*)(ur + 16 * ks + 4);
                uint4 d;
                d.x = pack_rn(lrelu(v0[0]+u0[0]), lrelu(v0[1]+u0[1]));
                d.y = pack_rn(lrelu(v0[2]+u0[2]), lrelu(v0[3]+u0[3]));
                d.z = pack_rn(lrelu(v1[0]+u1[0]), lrelu(v1[1]+u1[1]));
                d.w = pack_rn(lrelu(v1[2]+u1[2]), lrelu(v1[3]+u1[3]));
                B[ks] = d;
            }
        }

        #pragma unroll
        for (int nt = 0; nt < 4; nt++) {
            f32x16 a;
            #pragma unroll
            for (int ks = 0; ks < 9; ks++) {
                bf16x8 wf = *(const bf16x8*)&Wlds[(size_t)(ks * 256 + h * 128 + nt * 32 + lo) * 8];
                uint4 zu = (ks < 8) ? B[ks] : biasfrag;
                bf16x8 zf = *(bf16x8*)&zu;
                if (layer < 2)
                    a = __builtin_amdgcn_mfma_f32_32x32x16_bf16(wf, zf, ks ? a : Z, 0, 0, 0);
                else
                    a = __builtin_amdgcn_mfma_f32_32x32x16_bf16(zf, wf, ks ? a : Z, 0, 0, 0);
            }

            if (layer < 2) {
                u32 own[4][2], oth[4][2];
                #pragma unroll
                for (int c = 0; c < 4; c++)
                    #pragma unroll
                    for (int p = 0; p < 2; p++)
                        own[c][p] = pack_rn(lrelu(a[c + 8*p]),
                                            lrelu(a[c + 4 + 8*p]));
                #pragma unroll
                for (int c = 0; c < 4; c++)
                    #pragma unroll
                    for (int p = 0; p < 2; p++)
                        oth[c][p] = (u32)__shfl_xor((int)own[c][p], 32);
                #pragma unroll
                for (int p = 0; p < 2; p++) {
                    u32 dA0 = __builtin_amdgcn_perm(own[1][p], own[0][p], selv);
                    u32 dB0 = __builtin_amdgcn_perm(oth[1][p], oth[0][p], selv);
                    u32 dA1 = __builtin_amdgcn_perm(own[3][p], own[2][p], selv);
                    u32 dB1 = __builtin_amdgcn_perm(oth[3][p], oth[2][p], selv);
                    uint4 d;
                    d.x = h ? dB0 : dA0;
                    d.y = h ? dB1 : dA1;
                    d.z = h ? dA0 : dB0;
                    d.w = h ? dA1 : dB1;
                    Bn[2 * nt + p] = d;
                }
            } else {
                float t = 0.f;
                #pragma unroll
                for (int r = 0; r < 16; r++)
                    t += lrelu(a[r]);
                ssum[nt] = t;
            }
        }

        if (layer < 2) {
            #pragma unroll
            for (int ks = 0; ks < 8; ks++) B[ks] = Bn[ks];
        }
    }

    #pragma unroll
    for (int nt = 0; nt < 4; nt++) {
        float v = ssum[nt] + __shfl_xor(ssum[nt], 32);
        if (h == 0) atomicAdd(&spart[nt * 32 + lo], v);
    }
    __syncthreads();
    if (tid < 128) atomicAdd(&s_glob[b * 128 + tid], spart[tid]);
}

// ---------------------------------------------------------------------------
// Stage F: final MLP head (16 units).
// ---------------------------------------------------------------------------
__device__ __forceinline__ void final_block(int b, int tid, unsigned char* smem,
    const float* s_glob,
    const float* W5, const float* b5,
    const float* W6, const float* b6,
    float* out)
{
    float* sh = (float*)smem;
    float* t5 = (float*)(smem + 512);
    if (tid < 128) sh[tid] = s_glob[b * 128 + tid];
    __syncthreads();
    if (tid < 128) {
        const float* wr = W5 + (size_t)tid * 128;
        float acc = b5[tid];
        #pragma unroll
        for (int k = 0; k < 128; k += 4) {
            f32x4 wv = *(const f32x4*)(wr + k);
            f32x4 sv = *(const f32x4*)&sh[k];
            acc += wv[0]*sv[0] + wv[1]*sv[1] + wv[2]*sv[2] + wv[3]*sv[3];
        }
        t5[tid] = lrelu(acc);
    }
    __syncthreads();
    #pragma unroll
    for (int q = 0; q < 2; q++) {
        int o = q * 256 + tid;
        const float* wr = W6 + (size_t)o * 128;
        float acc = b6[o];
        #pragma unroll
        for (int k = 0; k < 128; k += 4) {
            f32x4 wv = *(const f32x4*)(wr + k);
            f32x4 tv = *(const f32x4*)&t5[k];
            acc += wv[0]*tv[0] + wv[1]*tv[1] + wv[2]*tv[2] + wv[3]*tv[3];
        }
        out[b * 512 + o] = lrelu(acc);
    }
}

// ---------------------------------------------------------------------------
// Cooperative mega-kernel: all stages, grid-size-agnostic strided loops,
// grid.sync() between stages.
// ---------------------------------------------------------------------------
__global__ __launch_bounds__(256, 4) void k_all(
    const float* __restrict__ x, const float* __restrict__ h,
    const float* __restrict__ conv_w, const float* __restrict__ conv_b,
    const float* __restrict__ bn_g, const float* __restrict__ bn_b,
    const float* __restrict__ W1, const float* __restrict__ b1,
    const float* __restrict__ W2, const float* __restrict__ b2,
    const float* __restrict__ W3, const float* __restrict__ b3,
    const float* __restrict__ W4, const float* __restrict__ b4,
    const float* __restrict__ W5, const float* __restrict__ b5,
    const float* __restrict__ W6, const float* __restrict__ b6,
    float* __restrict__ out, char* __restrict__ ws)
{
    __shared__ __align__(16) unsigned char smem[37376];
    int tid = threadIdx.x, wg = blockIdx.x, gdim = gridDim.x;
    cg::grid_group grid = cg::this_grid();

    float* s_glob = (float*)(ws);
    float* stats  = (float*)(ws + 8192);
    float* hW     = (float*)(ws + 10240);
    float* ws_y   = (float*)(ws + 18432);
    float* vv     = (float*)(ws + 2639872);
    float* uu     = (float*)(ws + 3950592);
    u16*   xb     = (u16*)  (ws + 5261312);
    u16*   wcb_f  = (u16*)  (ws + 7882752);
    u16*   wfrag  = (u16*)  (ws + 8669184);
    u16*   w1frag = (u16*)  (ws + 8779776);

    for (int g = wg; g < 1729; g += gdim)
        prep_block(g, tid, x, conv_w, W2, W3, W4, b2, b3, b4, h, W1,
                   xb, wcb_f, wfrag, w1frag, hW, s_glob);
    __threadfence();
    grid.sync();

    for (int u = wg; u < 640; u += gdim)
        conv_block(u, tid, (u16*)smem, xb, wcb_f, conv_b, ws_y, stats);
    __threadfence();
    grid.sync();

    for (int u = wg; u < 160; u += gdim)
        uv_block(u, tid, smem, ws_y, stats, bn_g, bn_b, w1frag, b1, hW, uu, vv);
    __threadfence();
    grid.sync();

    {
        u16*   Wlds  = (u16*)smem;
        float* spart = (float*)(smem + 36864);
        #pragma unroll 1
        for (int u = wg; u < 3200; u += gdim)
            mlp_unit(u, tid, Wlds, spart, vv, uu, wfrag, s_glob);
    }
    __threadfence();
    grid.sync();

    for (int u = wg; u < 16; u += gdim)
        final_block(u, tid, smem, s_glob, W5, b5, W6, b6, out);
}

// ---------------------------------------------------------------------------
// Fallback wrappers (r10 5-kernel pipeline; same stage bodies).
// ---------------------------------------------------------------------------
__global__ __launch_bounds__(256) void k_prep_g(
    const float* x, const float* conv_w,
    const float* W2, const float* W3, const float* W4,
    const float* b2, const float* b3, const float* b4,
    const float* h, const float* W1,
    u16* xb, u16* wcb_f, u16* wfrag, u16* w1frag, float* hW, float* zero0)
{
    prep_block(blockIdx.x, threadIdx.x, x, conv_w, W2, W3, W4, b2, b3, b4,
               h, W1, xb, wcb_f, wfrag, w1frag, hW, zero0);
}

__global__ __launch_bounds__(256, 4) void k_conv_g(
    const u16* xb, const u16* wcb_f, const float* conv_b,
    float* ws_y, float* stats)
{
    __shared__ u16 xs[18 * 520];
    conv_block(blockIdx.x, threadIdx.x, xs, xb, wcb_f, conv_b, ws_y, stats);
}

__global__ __launch_bounds__(256) void k_uv_g(
    const float* ws_y, const float* stats,
    const float* bn_g, const float* bn_b,
    const u16* w1frag, const float* b1, const float* hW,
    float* uu, float* vv)
{
    __shared__ __align__(16) unsigned char smem[2048 + 16 * 296 * 2];
    uv_block(blockIdx.x, threadIdx.x, smem, ws_y, stats, bn_g, bn_b,
             w1frag, b1, hW, uu, vv);
}

__global__ __launch_bounds__(256, 4) void k_mlp_g(
    const float* vv, const float* uu, const u16* wfrag, float* s_glob)
{
    __shared__ __align__(16) u16 Wlds[18432];
    __shared__ float spart[128];
    mlp_unit(blockIdx.x, threadIdx.x, Wlds, spart, vv, uu, wfrag, s_glob);
}

__global__ __launch_bounds__(256) void k_final_g(
    const float* s_glob, const float* W5, const float* b5,
    const float* W6, const float* b6, float* out)
{
    __shared__ __align__(16) unsigned char smem[1024];
    final_block(blockIdx.x, threadIdx.x, smem, s_glob, W5, b5, W6, b6, out);
}

// ---------------------------------------------------------------------------
extern "C" void kernel_launch(void* const* d_in, const int* in_sizes, int n_in,
                              void* d_out, int out_size, void* d_ws, size_t ws_size,
                              hipStream_t stream)
{
    const float* x      = (const float*)d_in[0];
    const float* h      = (const float*)d_in[1];
    const float* conv_w = (const float*)d_in[2];
    const float* conv_b = (const float*)d_in[3];
    const float* bn_g   = (const float*)d_in[4];
    const float* bn_b   = (const float*)d_in[5];
    const float* W1     = (const float*)d_in[6];
    const float* b1     = (const float*)d_in[7];
    const float* W2     = (const float*)d_in[8];
    const float* b2     = (const float*)d_in[9];
    const float* W3     = (const float*)d_in[10];
    const float* b3     = (const float*)d_in[11];
    const float* W4     = (const float*)d_in[12];
    const float* b4     = (const float*)d_in[13];
    const float* W5     = (const float*)d_in[14];
    const float* b5     = (const float*)d_in[15];
    const float* W6     = (const float*)d_in[16];
    const float* b6     = (const float*)d_in[17];
    float* out = (float*)d_out;
    char*  ws  = (char*)d_ws;

    float* s_glob = (float*)(ws);
    float* stats  = (float*)(ws + 8192);
    float* hW     = (float*)(ws + 10240);
    float* ws_y   = (float*)(ws + 18432);
    float* vv     = (float*)(ws + 2639872);
    float* uu     = (float*)(ws + 3950592);
    u16*   xb     = (u16*)  (ws + 5261312);
    u16*   wcb_f  = (u16*)  (ws + 7882752);
    u16*   wfrag  = (u16*)  (ws + 8669184);
    u16*   w1frag = (u16*)  (ws + 8779776);

    // Size the cooperative grid from the runtime's own occupancy model.
    int occ = 0;
    hipError_t qerr = hipOccupancyMaxActiveBlocksPerMultiprocessor(&occ, k_all, 256, 0);
    int grid = (qerr == hipSuccess && occ > 0) ? occ * 256 : 0;
    if (grid > 800) grid = 800;

    bool done = false;
    if (grid >= 256) {
        void* params[] = {
            (void*)&x, (void*)&h, (void*)&conv_w, (void*)&conv_b,
            (void*)&bn_g, (void*)&bn_b, (void*)&W1, (void*)&b1,
            (void*)&W2, (void*)&b2, (void*)&W3, (void*)&b3,
            (void*)&W4, (void*)&b4, (void*)&W5, (void*)&b5,
            (void*)&W6, (void*)&b6, (void*)&out, (void*)&ws
        };
        hipError_t lerr = hipLaunchCooperativeKernel(k_all, dim3(grid), dim3(256),
                                                     params, 0, stream);
        done = (lerr == hipSuccess);
    }

    if (!done) {   // fallback: r10 5-kernel pipeline
        k_prep_g <<<1729, 256, 0, stream>>>(x, conv_w, W2, W3, W4, b2, b3, b4,
                                            h, W1, xb, wcb_f, wfrag, w1frag, hW, s_glob);
        k_conv_g <<<640, 256, 0, stream>>>(xb, wcb_f, conv_b, ws_y, stats);
        k_uv_g   <<<160, 256, 0, stream>>>(ws_y, stats, bn_g, bn_b, w1frag, b1, hW, uu, vv);
        k_mlp_g  <<<3200, 256, 0, stream>>>(vv, uu, wfrag, s_glob);
        k_final_g<<<16, 256, 0, stream>>>(s_glob, W5, b5, W6, b6, out);
    }
}

// Round 13
// 381.064 us; speedup vs baseline: 1.9193x; 1.9193x over previous
//
#include <hip/hip_runtime.h>
#include <cstdint>

typedef unsigned short u16;
typedef uint32_t u32;

typedef __bf16 bf16x8 __attribute__((ext_vector_type(8)));
typedef float  f32x4  __attribute__((ext_vector_type(4)));
typedef float  f32x16 __attribute__((ext_vector_type(16)));
typedef u16    u16x4  __attribute__((ext_vector_type(4)));
typedef u16    u16x8  __attribute__((ext_vector_type(8)));

__device__ __forceinline__ u16 f2bf(float f) {
    u32 x = __float_as_uint(f);
    return (u16)((x + 0x7FFFu + ((x >> 16) & 1u)) >> 16);
}
__device__ __forceinline__ float lrelu(float x) { return fmaxf(x, 0.1f * x); }

__device__ __forceinline__ u32 pack_rn(float lo, float hi) {
    u32 a = __float_as_uint(lo) + 0x8000u;
    u32 b = __float_as_uint(hi) + 0x8000u;
    return __builtin_amdgcn_perm(b, a, 0x07060302u);
}

// ---------------------------------------------------------------------------
// k_prep (449 blocks): conv_w -> wcb_f frag order; W2/3/4+b -> wfrag;
// W1 -> w1frag; hW = h @ W1jh.T; zero s_glob+stats+ctr.  (xb eliminated —
// k_conv converts x on the fly.)
// ---------------------------------------------------------------------------
__global__ __launch_bounds__(256) void k_prep(
    const float* __restrict__ conv_w,
    const float* __restrict__ W2, const float* __restrict__ W3, const float* __restrict__ W4,
    const float* __restrict__ b2, const float* __restrict__ b3, const float* __restrict__ b4,
    const float* __restrict__ h, const float* __restrict__ W1,
    u16* __restrict__ wcb_f, u16* __restrict__ wfrag, u16* __restrict__ w1frag,
    float* __restrict__ hW, float* __restrict__ zero0, u32* __restrict__ ctr)
{
    int blk = blockIdx.x, tid = threadIdx.x;
    if (blk < 192) {                        // wcb_f: 49,152 frags of 16B
        int g = blk * 256 + tid;            // ((cb*48 + ks)*64 + lane)
        int lane = g & 63;
        int ks = (g >> 6) % 48;
        int cb = g / 3072;
        int c = cb * 16 + (lane & 15);
        int quad = lane >> 4;
        int k0 = ks * 32 + quad * 8;
        int tap = k0 >> 9, e0 = k0 & 511;
        u16x8 ov;
        #pragma unroll
        for (int j = 0; j < 8; j++)
            ov[j] = f2bf(conv_w[((size_t)c * 512 + e0 + j) * 3 + tap]);
        *(u16x8*)&wcb_f[(size_t)g * 8] = ov;
    } else if (blk < 246) {                 // wfrag: 55,296 elems, 54 blocks
        int o = ((blk - 192) * 256 + tid) * 4;
        int layer = o / 18432, rem = o % 18432;
        int ks9 = rem >> 11;
        int rem2 = rem & 2047;
        int hh = rem2 >> 10;
        int rem3 = rem2 & 1023;
        int n = rem3 >> 3, j0 = rem3 & 7;   // j0 in {0,4}
        const float* W = (layer == 0) ? W2 : (layer == 1) ? W3 : W4;
        const float* bi = (layer == 0) ? b2 : (layer == 1) ? b3 : b4;
        u16x4 ov;
        if (ks9 < 8) {
            f32x4 v = *(const f32x4*)(W + (size_t)n * 128 + 16 * ks9 + 8 * hh + j0);
            ov[0] = f2bf(v[0]); ov[1] = f2bf(v[1]); ov[2] = f2bf(v[2]); ov[3] = f2bf(v[3]);
        } else {
            ov[0] = (hh == 0 && j0 == 0) ? f2bf(bi[n]) : (u16)0;
            ov[1] = 0; ov[2] = 0; ov[3] = 0;
        }
        *(u16x4*)&wfrag[o] = ov;
    } else if (blk < 318) {                 // w1frag: 73,728 elems, 72 blocks
        int o = ((blk - 246) * 256 + tid) * 4;
        int nt = o / 4608;                  // 9*64*8
        int rem = o % 4608;
        int ks = rem >> 9;
        int rem2 = rem & 511;
        int lane = rem2 >> 3, j0 = rem2 & 7;
        int n = nt * 16 + (lane & 15);
        int k0 = ks * 32 + (lane >> 4) * 8 + j0;
        const float* wr = (n < 128) ? (W1 + (size_t)n * 1028)
                                    : (W1 + (size_t)(n - 128) * 1028 + 258);
        u16x4 ov;
        #pragma unroll
        for (int q = 0; q < 4; q++) {
            int k = k0 + q;
            ov[q] = (k < 258) ? f2bf(wr[k]) : (u16)0;
        }
        *(u16x4*)&w1frag[o] = ov;
    } else if (blk < 446) {                 // hW: 2048 outs x 16 lanes, 128 blocks
        int gid = (blk - 318) * 256 + tid;
        int outp = gid >> 4, q = gid & 15;
        int b = outp >> 7, d = outp & 127;
        const float* hr = h + (size_t)b * 512;
        const float* wr = W1 + (size_t)d * 1028 + 516;
        float acc = 0.f;
        #pragma unroll
        for (int c = 0; c < 8; c++) {
            int k = c * 64 + q * 4;
            f32x4 hv = *(const f32x4*)(hr + k);
            f32x4 wv = *(const f32x4*)(wr + k);
            acc += hv[0]*wv[0] + hv[1]*wv[1] + hv[2]*wv[2] + hv[3]*wv[3];
        }
        acc += __shfl_xor(acc, 1); acc += __shfl_xor(acc, 2);
        acc += __shfl_xor(acc, 4); acc += __shfl_xor(acc, 8);
        if (q == 0) hW[outp] = acc;
    } else {                                // zero s_glob(8KB)+stats(2KB)+ctr
        int idx = (blk - 446) * 256 + tid;
        if (idx < 640) {
            f32x4 z = {0.f, 0.f, 0.f, 0.f};
            *(f32x4*)&zero0[idx * 4] = z;
        }
        if (idx == 0) *ctr = 0u;
    }
}

// ---------------------------------------------------------------------------
// k_conv: conv1d (K=3, pad 1) as im2col GEMM, bf16 MFMA. x converted to bf16
// on the fly during LDS staging (identical f2bf rounding as the old xb path).
// 16-row tiles, 640 WGs.
// ---------------------------------------------------------------------------
__global__ __launch_bounds__(256, 4) void k_conv(
    const float* __restrict__ x, const u16* __restrict__ wcb_f,
    const float* __restrict__ conv_b,
    float* __restrict__ ws_y, float* __restrict__ stats)
{
    __shared__ u16 xs[18 * 520];
    int tid = threadIdx.x, wg = blockIdx.x;
    int rowtile = wg >> 2, cgp = wg & 3;
    int b = rowtile / 10, l0 = (rowtile % 10) * 16;

    for (int t = tid; t < 18 * 64; t += 256) {
        int s = t >> 6, ch = t & 63;
        int lg = l0 + s - 1;
        u16x8 ov = {};
        if (lg >= 0 && lg < 160) {
            const float* src = x + ((size_t)(lg * 16 + b)) * 512 + ch * 8;
            f32x4 v0 = *(const f32x4*)src;
            f32x4 v1 = *(const f32x4*)(src + 4);
            ov[0] = f2bf(v0[0]); ov[1] = f2bf(v0[1]);
            ov[2] = f2bf(v0[2]); ov[3] = f2bf(v0[3]);
            ov[4] = f2bf(v1[0]); ov[5] = f2bf(v1[1]);
            ov[6] = f2bf(v1[2]); ov[7] = f2bf(v1[3]);
        }
        *(u16x8*)&xs[s * 520 + ch * 8] = ov;
    }
    __syncthreads();

    int lane = tid & 63, w = tid >> 6;
    int row16 = lane & 15, quad = lane >> 4;
    int cb = cgp * 4 + w;
    int c_n = cb * 16 + row16;
    const u16* wb = wcb_f + (size_t)cb * 24576;   // 48*64*8

    f32x4 acc0 = {0,0,0,0};
    for (int ks4 = 0; ks4 < 48; ks4 += 4) {
        bf16x8 wf[4];
        #pragma unroll
        for (int q = 0; q < 4; q++)
            wf[q] = *(const bf16x8*)(wb + (size_t)((ks4 + q) * 64 + lane) * 8);
        #pragma unroll
        for (int q = 0; q < 4; q++) {
            int k = (ks4 + q) * 32 + quad * 8;
            int tap = k >> 9, e = k & 511;
            bf16x8 a0 = *(const bf16x8*)&xs[(row16 + tap) * 520 + e];
            acc0 = __builtin_amdgcn_mfma_f32_16x16x32_bf16(a0, wf[q], acc0, 0, 0, 0);
        }
    }

    float bias = conv_b[c_n];
    float sum = 0.f, sq = 0.f;
    #pragma unroll
    for (int r = 0; r < 4; r++) {
        float v = lrelu(acc0[r] + bias);
        int lr = l0 + quad * 4 + r;
        ws_y[((size_t)(b * 160 + lr)) * 256 + c_n] = v;
        sum += v; sq += v * v;
    }
    sum += __shfl_xor(sum, 16); sum += __shfl_xor(sum, 32);
    sq  += __shfl_xor(sq, 16);  sq  += __shfl_xor(sq, 32);
    if (quad == 0) {
        atomicAdd(&stats[c_n], sum);
        atomicAdd(&stats[256 + c_n], sq);
    }
}

// ---------------------------------------------------------------------------
// k_uv: BN + coords -> xf bf16 in LDS (K padded 258->288), u|v = xf @ W1T
// via 16x16x32 MFMA with pre-built w1frag B-frags. 16 rows/WG, 160 WGs.
// ---------------------------------------------------------------------------
__global__ __launch_bounds__(256) void k_uv(
    const float* __restrict__ ws_y, const float* __restrict__ stats,
    const float* __restrict__ bn_g, const float* __restrict__ bn_b,
    const u16* __restrict__ w1frag, const float* __restrict__ b1,
    const float* __restrict__ hW,
    float* __restrict__ uu, float* __restrict__ vv)
{
    __shared__ float a_s[256], c_s[256];
    __shared__ __align__(16) u16 xfs[16 * 296];
    int tid = threadIdx.x;
    int row0 = blockIdx.x * 16;
    int b = row0 / 160, l0 = row0 % 160;
    {
        int c = tid;
        float mu  = stats[c] * (1.0f / 2560.0f);
        float var = stats[256 + c] * (1.0f / 2560.0f) - mu * mu;
        float rs  = rsqrtf(var + 1e-5f) * bn_g[c];
        a_s[c] = rs;
        c_s[c] = bn_b[c] - mu * rs;
    }
    __syncthreads();
    float sLf = sqrtf(160.0f);
    for (int idx = tid; idx < 16 * 288; idx += 256) {
        int r = idx / 288, c = idx - r * 288;
        int l = l0 + r;
        float v = 0.f;
        if (c < 256) {
            v = ws_y[((size_t)(b * 160 + l)) * 256 + c] * a_s[c] + c_s[c];
        } else if (c == 256) {
            v = ((float)l / sLf - 2.0f) * 0.5f;
        } else if (c == 257) {
            float fi = (float)l;
            float m = fi - floorf(fi / sLf) * sLf;
            v = (m - 2.0f) * 0.5f;
        }
        xfs[r * 296 + c] = f2bf(v);
    }
    __syncthreads();

    int lane = tid & 63, w = tid >> 6;
    int row16 = lane & 15, quad = lane >> 4;

    bf16x8 af[9];
    #pragma unroll
    for (int ks = 0; ks < 9; ks++)
        af[ks] = *(const bf16x8*)&xfs[row16 * 296 + ks * 32 + quad * 8];

    #pragma unroll
    for (int nt = 0; nt < 4; nt++) {
        f32x4 a = {0.f, 0.f, 0.f, 0.f};
        #pragma unroll
        for (int ks = 0; ks < 9; ks++) {
            bf16x8 bf = *(const bf16x8*)(w1frag +
                (size_t)(((w * 4 + nt) * 9 + ks) * 64 + lane) * 8);
            a = __builtin_amdgcn_mfma_f32_16x16x32_bf16(af[ks], bf, a, 0, 0, 0);
        }
        int n = (w * 4 + nt) * 16 + row16;
        bool isv = n >= 128;
        int d = n & 127;
        float add = isv ? (hW[b * 128 + d] + b1[d]) : 0.f;
        float* dst = isv ? vv : uu;
        #pragma unroll
        for (int r = 0; r < 4; r++) {
            int l = l0 + quad * 4 + r;
            dst[((size_t)(b * 160 + l)) * 128 + d] = a[r] + add;
        }
    }
}

// ---------------------------------------------------------------------------
// k_mlp (+fused final head): r10 MLP body (T=1, per-nt chains, layer-2 flip,
// bias as 9th K-tile). After the s_glob flush, each WG bumps a device counter;
// the LAST WG (atomicAdd returns 3199) alone runs the final head for all 16
// batches, reading s_glob via device-scope atomic loads. No spins, no
// ordering assumptions -> no deadlock possible.
// ---------------------------------------------------------------------------
__global__ __launch_bounds__(256, 4) void k_mlp(
    const float* __restrict__ vv, const float* __restrict__ uu,
    const u16* __restrict__ wfrag,
    float* __restrict__ s_glob, u32* __restrict__ ctr,
    const float* __restrict__ W5, const float* __restrict__ b5,
    const float* __restrict__ W6, const float* __restrict__ b6,
    float* __restrict__ out)
{
    __shared__ __align__(16) u16 Wlds[18432];   // [ks9][h][n][8]
    __shared__ float spart[128];
    __shared__ float fin[256];                  // sh[128] | t5[128]
    __shared__ bool lastflag;
    int tid = threadIdx.x;
    int wave = tid >> 6, lane = tid & 63;
    int h = lane >> 5, lo = lane & 31;
    int b = blockIdx.x / 200, sub = blockIdx.x % 200;
    int tileb = sub * 4 + wave;

    if (tid < 128) spart[tid] = 0.f;

    u32 selv = h ? 0x07060302u : 0x05040100u;
    uint4 biasfrag;
    biasfrag.x = (h == 0) ? 0x00003F80u : 0u;   // bf16 1.0 at j=0, h=0
    biasfrag.y = 0u; biasfrag.z = 0u; biasfrag.w = 0u;

    f32x16 Z;
    #pragma unroll
    for (int r = 0; r < 16; r++) Z[r] = 0.f;

    uint4 B[8], Bn[8];
    float ssum[4];

    int i  = (tileb / 10) * 2  + (lo >> 4);
    int jj = (tileb % 10) * 16 + (lo & 15);
    const float* vr = vv + ((size_t)(b * 160 + i))  * 128 + 8 * h;
    const float* ur = uu + ((size_t)(b * 160 + jj)) * 128 + 8 * h;

    for (int layer = 0; layer < 3; layer++) {
        __syncthreads();
        {
            const uint4* src = (const uint4*)(wfrag + layer * 18432);
            #pragma unroll
            for (int it = 0; it < 9; it++) {
                int idx = it * 256 + tid;
                *(uint4*)&Wlds[idx * 8] = src[idx];
            }
        }
        __syncthreads();

        if (layer == 0) {
            #pragma unroll
            for (int ks = 0; ks < 8; ks++) {
                f32x4 v0 = *(const f32x4*)(vr + 16 * ks);
                f32x4 v1 = *(const f32x4*)(vr + 16 * ks + 4);
                f32x4 u0 = *(const f32x4*)(ur + 16 * ks);
                f32x4 u1 = *(const f32x4*)(ur + 16 * ks + 4);
                uint4 d;
                d.x = pack_rn(lrelu(v0[0]+u0[0]), lrelu(v0[1]+u0[1]));
                d.y = pack_rn(lrelu(v0[2]+u0[2]), lrelu(v0[3]+u0[3]));
                d.z = pack_rn(lrelu(v1[0]+u1[0]), lrelu(v1[1]+u1[1]));
                d.w = pack_rn(lrelu(v1[2]+u1[2]), lrelu(v1[3]+u1[3]));
                B[ks] = d;
            }
        }

        #pragma unroll
        for (int nt = 0; nt < 4; nt++) {
            f32x16 a;
            #pragma unroll
            for (int ks = 0; ks < 9; ks++) {
                bf16x8 wf = *(const bf16x8*)&Wlds[(size_t)(ks * 256 + h * 128 + nt * 32 + lo) * 8];
                uint4 zu = (ks < 8) ? B[ks] : biasfrag;
                bf16x8 zf = *(bf16x8*)&zu;
                if (layer < 2)
                    a = __builtin_amdgcn_mfma_f32_32x32x16_bf16(wf, zf, ks ? a : Z, 0, 0, 0);
                else
                    a = __builtin_amdgcn_mfma_f32_32x32x16_bf16(zf, wf, ks ? a : Z, 0, 0, 0);
            }

            if (layer < 2) {
                u32 own[4][2], oth[4][2];
                #pragma unroll
                for (int c = 0; c < 4; c++)
                    #pragma unroll
                    for (int p = 0; p < 2; p++)
                        own[c][p] = pack_rn(lrelu(a[c + 8*p]),
                                            lrelu(a[c + 4 + 8*p]));
                #pragma unroll
                for (int c = 0; c < 4; c++)
                    #pragma unroll
                    for (int p = 0; p < 2; p++)
                        oth[c][p] = (u32)__shfl_xor((int)own[c][p], 32);
                #pragma unroll
                for (int p = 0; p < 2; p++) {
                    u32 dA0 = __builtin_amdgcn_perm(own[1][p], own[0][p], selv);
                    u32 dB0 = __builtin_amdgcn_perm(oth[1][p], oth[0][p], selv);
                    u32 dA1 = __builtin_amdgcn_perm(own[3][p], own[2][p], selv);
                    u32 dB1 = __builtin_amdgcn_perm(oth[3][p], oth[2][p], selv);
                    uint4 d;
                    d.x = h ? dB0 : dA0;
                    d.y = h ? dB1 : dA1;
                    d.z = h ? dA0 : dB0;
                    d.w = h ? dA1 : dB1;
                    Bn[2 * nt + p] = d;
                }
            } else {
                float t = 0.f;
                #pragma unroll
                for (int r = 0; r < 16; r++)
                    t += lrelu(a[r]);
                ssum[nt] = t;
            }
        }

        if (layer < 2) {
            #pragma unroll
            for (int ks = 0; ks < 8; ks++) B[ks] = Bn[ks];
        }
    }

    #pragma unroll
    for (int nt = 0; nt < 4; nt++) {
        float v = ssum[nt] + __shfl_xor(ssum[nt], 32);
        if (h == 0) atomicAdd(&spart[nt * 32 + lo], v);
    }
    __syncthreads();
    if (tid < 128) atomicAdd(&s_glob[b * 128 + tid], spart[tid]);

    // ---- fused final head: last WG to finish does it for all batches ----
    __syncthreads();
    if (tid == 0) {
        __threadfence();                    // order s_glob atomics before ctr
        u32 prev = atomicAdd(ctr, 1u);
        lastflag = (prev == 3199u);
    }
    __syncthreads();
    if (!lastflag) return;
    __threadfence();

    float* sh = fin;
    float* t5 = fin + 128;
    for (int bb = 0; bb < 16; bb++) {
        if (tid < 128)
            sh[tid] = __hip_atomic_load(&s_glob[bb * 128 + tid],
                                        __ATOMIC_RELAXED, __HIP_MEMORY_SCOPE_AGENT);
        __syncthreads();
        if (tid < 128) {
            const float* wr = W5 + (size_t)tid * 128;
            float acc = b5[tid];
            #pragma unroll
            for (int k = 0; k < 128; k += 4) {
                f32x4 wv = *(const f32x4*)(wr + k);
                f32x4 sv = *(const f32x4*)&sh[k];
                acc += wv[0]*sv[0] + wv[1]*sv[1] + wv[2]*sv[2] + wv[3]*sv[3];
            }
            t5[tid] = lrelu(acc);
        }
        __syncthreads();
        #pragma unroll
        for (int q = 0; q < 2; q++) {
            int o = q * 256 + tid;
            const float* wr = W6 + (size_t)o * 128;
            float acc = b6[o];
            #pragma unroll
            for (int k = 0; k < 128; k += 4) {
                f32x4 wv = *(const f32x4*)(wr + k);
                f32x4 tv = *(const f32x4*)&t5[k];
                acc += wv[0]*tv[0] + wv[1]*tv[1] + wv[2]*tv[2] + wv[3]*tv[3];
            }
            out[bb * 512 + o] = lrelu(acc);
        }
        __syncthreads();
    }
}

// ---------------------------------------------------------------------------
extern "C" void kernel_launch(void* const* d_in, const int* in_sizes, int n_in,
                              void* d_out, int out_size, void* d_ws, size_t ws_size,
                              hipStream_t stream)
{
    const float* x      = (const float*)d_in[0];
    const float* h      = (const float*)d_in[1];
    const float* conv_w = (const float*)d_in[2];
    const float* conv_b = (const float*)d_in[3];
    const float* bn_g   = (const float*)d_in[4];
    const float* bn_b   = (const float*)d_in[5];
    const float* W1     = (const float*)d_in[6];
    const float* b1     = (const float*)d_in[7];
    const float* W2     = (const float*)d_in[8];
    const float* b2     = (const float*)d_in[9];
    const float* W3     = (const float*)d_in[10];
    const float* b3     = (const float*)d_in[11];
    const float* W4     = (const float*)d_in[12];
    const float* b4     = (const float*)d_in[13];
    const float* W5     = (const float*)d_in[14];
    const float* b5     = (const float*)d_in[15];
    const float* W6     = (const float*)d_in[16];
    const float* b6     = (const float*)d_in[17];
    float* out = (float*)d_out;
    char*  ws  = (char*)d_ws;

    float* s_glob = (float*)(ws);              //  8 KB
    float* stats  = (float*)(ws + 8192);       //  2 KB
    float* hW     = (float*)(ws + 10240);      //  8 KB
    float* ws_y   = (float*)(ws + 18432);      //  2.62 MB
    float* vv     = (float*)(ws + 2639872);    //  1.31 MB
    float* uu     = (float*)(ws + 3950592);    //  1.31 MB
    u16*   wcb_f  = (u16*)  (ws + 7882752);    //  786 KB (frag order)
    u16*   wfrag  = (u16*)  (ws + 8669184);    //  110.6 KB
    u16*   w1frag = (u16*)  (ws + 8779776);    //  147.5 KB
    u32*   ctr    = (u32*)  (ws + 8927232);    //  4 B (end 8,927,236)

    k_prep <<<449, 256, 0, stream>>>(conv_w, W2, W3, W4, b2, b3, b4, h, W1,
                                     wcb_f, wfrag, w1frag, hW, s_glob, ctr);
    k_conv <<<640, 256, 0, stream>>>(x, wcb_f, conv_b, ws_y, stats);
    k_uv   <<<160, 256, 0, stream>>>(ws_y, stats, bn_g, bn_b, w1frag, b1, hW, uu, vv);
    k_mlp  <<<3200, 256, 0, stream>>>(vv, uu, wfrag, s_glob, ctr,
                                      W5, b5, W6, b6, out);
}